// Round 8
// baseline (322.049 us; speedup 1.0000x reference)
//
#include <hip/hip_runtime.h>
#include <hip/hip_bf16.h>

#define BB 4
#define CC 128
#define NN 4096
#define NHEAD 4
#define HDIM 32
#define KSPLIT 4   // attention m-dim split for occupancy

typedef short bf16x8_t __attribute__((ext_vector_type(8)));  // 8 bf16 (4 VGPRs)
typedef float f32x4_t __attribute__((ext_vector_type(4)));
typedef int i32x4_t __attribute__((ext_vector_type(4)));

#define MFMA16(a, b, c) __builtin_amdgcn_mfma_f32_16x16x32_bf16(a, b, c, 0, 0, 0)
#define EXP2(x) __builtin_amdgcn_exp2f(x)

// scores use exp2: fold log2(e) into q scale (softmax invariant)
#define QSCALE (0.17677669529663687f * 1.4426950408889634f)

// RNE float->bf16 (finite inputs only)
static __device__ inline unsigned short f2bf(float f) {
  unsigned u = __builtin_bit_cast(unsigned, f);
  u += 0x7fffu + ((u >> 16) & 1u);
  return (unsigned short)(u >> 16);
}
static __device__ inline unsigned pk2(float lo, float hi) {  // RNE pack pair
  return (unsigned)f2bf(lo) | ((unsigned)f2bf(hi) << 16);
}
// pack two f32 -> bf16 pair by TRUNCATION: single v_perm_b32
static __device__ inline unsigned pack_trunc(float lo, float hi) {
  return __builtin_amdgcn_perm(__builtin_bit_cast(unsigned, hi),
                               __builtin_bit_cast(unsigned, lo), 0x07060302u);
}
static __device__ inline float bfu_lo(unsigned v) {
  return __builtin_bit_cast(float, v << 16);
}
static __device__ inline float bfu_hi(unsigned v) {
  return __builtin_bit_cast(float, v & 0xFFFF0000u);
}

// async global->LDS, 16 B per lane. gsrc is PER-LANE (gather); LDS dest =
// uniform base + lane*16.
static __device__ inline void gload_lds16(const unsigned short* gsrc, void* ldst) {
  __builtin_amdgcn_global_load_lds(
      (const __attribute__((address_space(1))) unsigned int*)gsrc,
      (__attribute__((address_space(3))) unsigned int*)ldst, 16, 0, 0);
}

// ---------------------------------------------------------------------------
// W conversion: wq(*QSCALE), wk, wv, wo fp32 -> bf16, contiguous in wb.
// ---------------------------------------------------------------------------
__global__ __launch_bounds__(256) void wconv_kernel(
    const float* __restrict__ wq, const float* __restrict__ wk,
    const float* __restrict__ wv, const float* __restrict__ wo,
    unsigned short* __restrict__ wb) {
  int f = (blockIdx.x * 256 + threadIdx.x) * 8;  // 32 blocks -> 65536 elems
  int m = f >> 14, off = f & 16383;
  const float* src = (m == 0) ? wq : (m == 1) ? wk : (m == 2) ? wv : wo;
  float sc = (m == 0) ? QSCALE : 1.0f;
  float4 a = *(const float4*)(src + off);
  float4 b = *(const float4*)(src + off + 4);
  ushort4 u0, u1;
  u0.x = f2bf(a.x * sc); u0.y = f2bf(a.y * sc); u0.z = f2bf(a.z * sc); u0.w = f2bf(a.w * sc);
  u1.x = f2bf(b.x * sc); u1.y = f2bf(b.y * sc); u1.z = f2bf(b.z * sc); u1.w = f2bf(b.w * sc);
  *(ushort4*)(wb + f) = u0;
  *(ushort4*)(wb + f + 4) = u1;
}

// ---------------------------------------------------------------------------
// QKV projection via MFMA. Grid (64 ntiles, B, 3 proj x 2 ot-halves = 6) —
// round 8: ot-halving doubles blocks/CU (3 -> 6) for latency hiding.
//   Q/K: [b][h][dblk=d/8][n][8d] bf16 via shfl-paired uint4 stores.
//   V:   LDS transpose -> vg gathered tiles, sequential uint4.
// ---------------------------------------------------------------------------
__global__ __launch_bounds__(256) void qkv_mfma_kernel(
    const float* __restrict__ x,
    const unsigned short* __restrict__ wqb, const unsigned short* __restrict__ wkb,
    const unsigned short* __restrict__ wvb,
    const float* __restrict__ bq, const float* __restrict__ bk,
    const float* __restrict__ bv,
    unsigned short* __restrict__ qt, unsigned short* __restrict__ kt,
    unsigned short* __restrict__ vg) {
  __shared__ __attribute__((aligned(16))) unsigned short xsb[64][136];  // [n][c] bf16
  __shared__ unsigned short vt[64][66];                                 // [o_local][n] bf16
  const int b = blockIdx.y, nt = blockIdx.x;
  const int proj = blockIdx.z >> 1, half = blockIdx.z & 1;
  const int tid = threadIdx.x;

#pragma unroll
  for (int i = 0; i < 8; i++) {
    int f = tid + 256 * i;               // 0..2047 float4-slots
    int c = f >> 4, n4 = (f & 15) * 4;
    float4 v4 = *(const float4*)(x + ((size_t)b * CC + c) * NN + nt * 64 + n4);
    xsb[n4 + 0][c] = f2bf(v4.x);
    xsb[n4 + 1][c] = f2bf(v4.y);
    xsb[n4 + 2][c] = f2bf(v4.z);
    xsb[n4 + 3][c] = f2bf(v4.w);
  }
  __syncthreads();

  const int lane = tid & 63, w = tid >> 6;
  const int l16 = lane & 15, g = lane >> 4;
  const int nl = w * 16;
  const int ngl = nt * 64 + nl;

  bf16x8_t xf[4];
#pragma unroll
  for (int ks = 0; ks < 4; ks++)
    xf[ks] = *(const bf16x8_t*)&xsb[nl + l16][ks * 32 + g * 8];

  const unsigned short* wm = (proj == 0) ? wqb : (proj == 1) ? wkb : wvb;
  const float* bias = (proj == 0) ? bq : (proj == 1) ? bk : bv;
  const float bsc = (proj == 0) ? QSCALE : 1.0f;
  unsigned short* qkdst = proj ? kt : qt;

#pragma unroll
  for (int i = 0; i < 4; i++) {
    const int ot = half * 4 + i;
    f32x4_t acc;
#pragma unroll
    for (int r = 0; r < 4; r++) acc[r] = bias[ot * 16 + g * 4 + r] * bsc;
#pragma unroll
    for (int ks = 0; ks < 4; ks++) {
      bf16x8_t wf = *(const bf16x8_t*)(wm + (size_t)(ot * 16 + l16) * CC + ks * 32 + g * 8);
      acc = MFMA16(wf, xf[ks], acc);
    }
    if (proj < 2) {
      unsigned p0 = pk2(acc[0], acc[1]);
      unsigned p1 = pk2(acc[2], acc[3]);
      unsigned q0 = (unsigned)__shfl_xor((int)p0, 16);
      unsigned q1 = (unsigned)__shfl_xor((int)p1, 16);
      if ((g & 1) == 0) {
        int hh = ot >> 1, dblk = (ot & 1) * 2 + (g >> 1);
        unsigned short* dst =
            qkdst + (((size_t)(b * NHEAD + hh) * 4 + dblk) * NN + ngl + l16) * 8;
        uint4 val = make_uint4(p0, p1, q0, q1);
        *(uint4*)dst = val;
      }
    } else {
#pragma unroll
      for (int r = 0; r < 4; r++) vt[i * 16 + g * 4 + r][nl + l16] = f2bf(acc[r]);
    }
  }

  if (proj == 2) {
    __syncthreads();
    // emit this half's vg chunks: 512 16B chunks, sequential stores
#pragma unroll
    for (int c = 0; c < 2; c++) {
      int cid = c * 256 + tid;               // 0..511
      int hh_l = cid >> 8, inner = cid & 255;
      int hh = half * 2 + hh_l;
      int g2 = inner & 3, l16v = (inner >> 2) & 15, fh = inner >> 6;
      int fv = fh >> 1, halfv = fh & 1;
      int o_l = hh_l * 32 + halfv * 16 + l16v;   // local row in vt
      int n0 = fv * 32 + g2 * 4;
      unsigned d0 = *(const unsigned*)&vt[o_l][n0];
      unsigned d1 = *(const unsigned*)&vt[o_l][n0 + 2];
      unsigned d2 = *(const unsigned*)&vt[o_l][n0 + 16];
      unsigned d3 = *(const unsigned*)&vt[o_l][n0 + 18];
      uint4 val = make_uint4(d0, d1, d2, d3);
      *(uint4*)(vg + (((size_t)(b * NHEAD + hh) * 64 + nt) * 256 + inner) * 8) = val;
    }
  }
}

// ---------------------------------------------------------------------------
// Flash attention, bf16 MFMA, no online max (|scores| << 1, verified r2-7).
// ROUND 8: KSPLIT=4, launch_bounds(256,8) -> 8 blocks/CU (32 waves/CU);
// l via VALU adds (frees ~20% of the matrix pipe); partial O written as
// bf16 dword pairs (n, n+16) -> half the partial traffic.
// ---------------------------------------------------------------------------
__global__ __launch_bounds__(256, 8) void attn_mfma6_kernel(
    const unsigned short* __restrict__ qt, const unsigned short* __restrict__ kt,
    const unsigned short* __restrict__ vg,
    unsigned* __restrict__ obf, float* __restrict__ lpart) {
  __shared__ __attribute__((aligned(16))) unsigned short smem[2][4096];  // [buf]: K 2048, V 2048

  const int chunk = blockIdx.x & (KSPLIT - 1), nt = blockIdx.x / KSPLIT;  // nt 0..31
  const int h = blockIdx.y, b = blockIdx.z;
  const int bh = b * NHEAD + h;
  const int tid = threadIdx.x, lane = tid & 63, wid = tid >> 6;
  const int l16 = lane & 15, g = lane >> 4;
  const int nbase = nt * 128 + wid * 32;

  const unsigned short* qb = qt + (size_t)bh * NN * HDIM;  // [dblk][n][8]
  const unsigned short* kb = kt + (size_t)bh * NN * HDIM;
  const unsigned short* vgb = vg + (size_t)bh * 64 * 2048;

  const bf16x8_t qf0 = *(const bf16x8_t*)(qb + ((size_t)g * NN + nbase + l16) * 8);
  const bf16x8_t qf1 = *(const bf16x8_t*)(qb + ((size_t)g * NN + nbase + 16 + l16) * 8);

  f32x4_t o00 = {0, 0, 0, 0}, o01 = {0, 0, 0, 0};  // t0: d=g*4+r, d+16
  f32x4_t o10 = {0, 0, 0, 0}, o11 = {0, 0, 0, 0};  // t1
  float lA = 0.f, lB = 0.f;
  const f32x4_t zf = {0, 0, 0, 0};

  const int NITER = 64 / KSPLIT;        // 16
  const int mt0 = chunk * NITER;

  const unsigned short* ksrc = kb + ((size_t)g * NN + mt0 * 64 + wid * 16 + l16) * 8;
  const unsigned short* vsrc = vgb + (size_t)mt0 * 2048 + (size_t)((wid * 16 + l16) * 4 + g) * 8;

  auto stage = [&](int p, int i) {
    gload_lds16(ksrc + (size_t)i * 512, &smem[p][wid * 512]);
    gload_lds16(vsrc + (size_t)i * 2048, &smem[p][2048 + wid * 512]);
  };

  auto body = [&](int p) {
    const unsigned short* sk = &smem[p][0];
    bf16x8_t k0 = *(const bf16x8_t*)(sk + 0 * 512 + lane * 8);
    bf16x8_t k1 = *(const bf16x8_t*)(sk + 1 * 512 + lane * 8);
    bf16x8_t k2 = *(const bf16x8_t*)(sk + 2 * 512 + lane * 8);
    bf16x8_t k3 = *(const bf16x8_t*)(sk + 3 * 512 + lane * 8);
    bf16x8_t vf0 = *(const bf16x8_t*)(sk + 2048 + 0 * 512 + lane * 8);  // f0,h0
    bf16x8_t vf2 = *(const bf16x8_t*)(sk + 2048 + 1 * 512 + lane * 8);  // f0,h1
    bf16x8_t vf1 = *(const bf16x8_t*)(sk + 2048 + 2 * 512 + lane * 8);  // f1,h0
    bf16x8_t vf3 = *(const bf16x8_t*)(sk + 2048 + 3 * 512 + lane * 8);  // f1,h1

    f32x4_t sA0 = MFMA16(k0, qf0, zf), sA1 = MFMA16(k1, qf0, zf);
    f32x4_t sA2 = MFMA16(k2, qf0, zf), sA3 = MFMA16(k3, qf0, zf);
    f32x4_t sB0 = MFMA16(k0, qf1, zf), sB1 = MFMA16(k1, qf1, zf);
    f32x4_t sB2 = MFMA16(k2, qf1, zf), sB3 = MFMA16(k3, qf1, zf);

#pragma unroll
    for (int r = 0; r < 4; r++) {
      sA0[r] = EXP2(sA0[r]); sA1[r] = EXP2(sA1[r]);
      sA2[r] = EXP2(sA2[r]); sA3[r] = EXP2(sA3[r]);
      sB0[r] = EXP2(sB0[r]); sB1[r] = EXP2(sB1[r]);
      sB2[r] = EXP2(sB2[r]); sB3[r] = EXP2(sB3[r]);
      lA += (sA0[r] + sA1[r]) + (sA2[r] + sA3[r]);
      lB += (sB0[r] + sB1[r]) + (sB2[r] + sB3[r]);
    }

    i32x4_t pA0i = {(int)pack_trunc(sA0[0], sA0[1]), (int)pack_trunc(sA0[2], sA0[3]),
                    (int)pack_trunc(sA1[0], sA1[1]), (int)pack_trunc(sA1[2], sA1[3])};
    i32x4_t pA1i = {(int)pack_trunc(sA2[0], sA2[1]), (int)pack_trunc(sA2[2], sA2[3]),
                    (int)pack_trunc(sA3[0], sA3[1]), (int)pack_trunc(sA3[2], sA3[3])};
    i32x4_t pB0i = {(int)pack_trunc(sB0[0], sB0[1]), (int)pack_trunc(sB0[2], sB0[3]),
                    (int)pack_trunc(sB1[0], sB1[1]), (int)pack_trunc(sB1[2], sB1[3])};
    i32x4_t pB1i = {(int)pack_trunc(sB2[0], sB2[1]), (int)pack_trunc(sB2[2], sB2[3]),
                    (int)pack_trunc(sB3[0], sB3[1]), (int)pack_trunc(sB3[2], sB3[3])};
    bf16x8_t pA0 = __builtin_bit_cast(bf16x8_t, pA0i);
    bf16x8_t pA1 = __builtin_bit_cast(bf16x8_t, pA1i);
    bf16x8_t pB0 = __builtin_bit_cast(bf16x8_t, pB0i);
    bf16x8_t pB1 = __builtin_bit_cast(bf16x8_t, pB1i);

    o00 = MFMA16(vf0, pA0, o00); o00 = MFMA16(vf1, pA1, o00);
    o01 = MFMA16(vf2, pA0, o01); o01 = MFMA16(vf3, pA1, o01);
    o10 = MFMA16(vf0, pB0, o10); o10 = MFMA16(vf1, pB1, o10);
    o11 = MFMA16(vf2, pB0, o11); o11 = MFMA16(vf3, pB1, o11);
  };

  stage(0, 0);
  __syncthreads();
  for (int mi = 0; mi < NITER; mi += 2) {
    stage(1, mi + 1);
    body(0);
    __syncthreads();
    if (mi + 2 < NITER) stage(0, mi + 2);
    body(1);
    __syncthreads();
  }

  // l: lane-partial over its 16 m per col; reduce across the 4 g-quads
  lA += __shfl_xor(lA, 16); lA += __shfl_xor(lA, 32);
  lB += __shfl_xor(lB, 16); lB += __shfl_xor(lB, 32);

  // partial O as bf16 dword pairs: obf[(chunk*16+bh)*32d*2048 + d*2048 + dw]
  // dword dw = nbase/2 + l16 packs (n = nbase+l16, n+16)
  unsigned* ob = obf + (size_t)(chunk * BB * NHEAD + bh) * 32 * 2048;
  const int dw = (nbase >> 1) + l16;
#pragma unroll
  for (int r = 0; r < 4; r++) {
    ob[(size_t)(g * 4 + r) * 2048 + dw] = pk2(o00[r], o10[r]);
    ob[(size_t)(16 + g * 4 + r) * 2048 + dw] = pk2(o01[r], o11[r]);
  }
  if (g == 0) {
    float* lb_ = lpart + (size_t)(chunk * BB * NHEAD + bh) * NN;
    lb_[nbase + l16] = lA;
    lb_[nbase + 16 + l16] = lB;
  }
}

// ---------------------------------------------------------------------------
// Combine: sum KSPLIT bf16 partials, normalize, write attnT[b][n][c] bf16.
// Grid (8 dword-tiles, 16 bh, 4 dg). Thread handles one dword = 2 n.
// ---------------------------------------------------------------------------
__global__ __launch_bounds__(256) void combine_kernel(
    const unsigned* __restrict__ obf, const float* __restrict__ lpart,
    unsigned short* __restrict__ attnT) {
  const int dw = blockIdx.x * 256 + threadIdx.x;  // 0..2047
  const int bh = blockIdx.y, dg = blockIdx.z;
  const int b = bh >> 2, h = bh & 3;
  const int n0 = ((dw >> 4) << 5) + (dw & 15), n1 = n0 + 16;

  float l0 = 0.f, l1 = 0.f;
#pragma unroll
  for (int c = 0; c < KSPLIT; c++) {
    const float* lp = lpart + (size_t)(c * BB * NHEAD + bh) * NN;
    l0 += lp[n0];
    l1 += lp[n1];
  }
  float inv0 = 1.f / l0, inv1 = 1.f / l1;

  float s0[8], s1[8];
#pragma unroll
  for (int j = 0; j < 8; j++) { s0[j] = 0.f; s1[j] = 0.f; }
#pragma unroll
  for (int c = 0; c < KSPLIT; c++) {
    const unsigned* ob =
        obf + (size_t)(c * BB * NHEAD + bh) * 32 * 2048 + (size_t)dg * 8 * 2048 + dw;
#pragma unroll
    for (int j = 0; j < 8; j++) {
      unsigned v = ob[(size_t)j * 2048];
      s0[j] += bfu_lo(v);
      s1[j] += bfu_hi(v);
    }
  }
  unsigned w0[4], w1[4];
#pragma unroll
  for (int p = 0; p < 4; p++) {
    w0[p] = pk2(s0[2 * p] * inv0, s0[2 * p + 1] * inv0);
    w1[p] = pk2(s1[2 * p] * inv1, s1[2 * p + 1] * inv1);
  }
  unsigned short* d0 = attnT + ((size_t)b * NN + n0) * CC + h * HDIM + dg * 8;
  unsigned short* d1 = attnT + ((size_t)b * NN + n1) * CC + h * HDIM + dg * 8;
  *(uint4*)d0 = *(uint4*)&w0[0];
  *(uint4*)d1 = *(uint4*)&w1[0];
}

// ---------------------------------------------------------------------------
// Output projection via MFMA + bias + residual, fp32 out.
// Grid (64 ntiles, B, 4 channel-quarters).
// ---------------------------------------------------------------------------
__global__ __launch_bounds__(256) void out_mfma_kernel(
    const unsigned short* __restrict__ attnT, const unsigned short* __restrict__ wob,
    const float* __restrict__ bo, const float* __restrict__ x,
    float* __restrict__ out) {
  const int b = blockIdx.y, nt = blockIdx.x, quarter = blockIdx.z;
  const int tid = threadIdx.x, lane = tid & 63, w = tid >> 6;
  const int l16 = lane & 15, g = lane >> 4;
  const int n0 = nt * 64 + w * 16;

  bf16x8_t bf[4];
#pragma unroll
  for (int ks = 0; ks < 4; ks++)
    bf[ks] = *(const bf16x8_t*)(attnT + ((size_t)b * NN + n0 + l16) * CC + ks * 32 + g * 8);

#pragma unroll
  for (int mi = 0; mi < 2; mi++) {
    int mt = quarter * 2 + mi;
    f32x4_t acc;
#pragma unroll
    for (int r = 0; r < 4; r++) acc[r] = bo[mt * 16 + g * 4 + r];
#pragma unroll
    for (int ks = 0; ks < 4; ks++) {
      bf16x8_t af = *(const bf16x8_t*)(wob + (size_t)(mt * 16 + l16) * CC + ks * 32 + g * 8);
      acc = MFMA16(af, bf[ks], acc);
    }
#pragma unroll
    for (int r = 0; r < 4; r++) {
      int o = mt * 16 + g * 4 + r;
      size_t addr = ((size_t)b * CC + o) * NN + n0 + l16;
      out[addr] = acc[r] + x[addr];
    }
  }
}

extern "C" void kernel_launch(void* const* d_in, const int* in_sizes, int n_in,
                              void* d_out, int out_size, void* d_ws, size_t ws_size,
                              hipStream_t stream) {
  const float* x  = (const float*)d_in[0];
  const float* wq = (const float*)d_in[1];
  const float* bq = (const float*)d_in[2];
  const float* wk = (const float*)d_in[3];
  const float* bk = (const float*)d_in[4];
  const float* wv = (const float*)d_in[5];
  const float* bv = (const float*)d_in[6];
  const float* wo = (const float*)d_in[7];
  const float* bo = (const float*)d_in[8];
  float* out = (float*)d_out;

  char* w = (char*)d_ws;
  const size_t SZ = (size_t)BB * NHEAD * NN * HDIM * 2;  // 4 MB (bf16 buffer bytes)
  unsigned short* qt    = (unsigned short*)w;            // 4 MB (attnT aliases later)
  unsigned short* kt    = (unsigned short*)(w + SZ);     // 4 MB
  unsigned short* vg    = (unsigned short*)(w + 2 * SZ); // 4 MB (gathered V)
  unsigned short* wb    = (unsigned short*)(w + 3 * SZ); // 128 KB
  unsigned* obf = (unsigned*)(w + 3 * SZ + 131072);      // KSPLIT * 4 MB = 16 MB
  float* lpart = (float*)(w + 3 * SZ + 131072 +
                          (size_t)KSPLIT * BB * NHEAD * HDIM * NN * 2);  // KSPLIT * 256 KB
  unsigned short* attnT = qt;  // qt is dead once attention completes
  unsigned short* wqb = wb, *wkb = wb + 16384, *wvb = wb + 32768, *wob = wb + 49152;

  wconv_kernel<<<32, 256, 0, stream>>>(wq, wk, wv, wo, wb);
  qkv_mfma_kernel<<<dim3(NN / 64, BB, 6), 256, 0, stream>>>(
      x, wqb, wkb, wvb, bq, bk, bv, qt, kt, vg);
  attn_mfma6_kernel<<<dim3((NN / 128) * KSPLIT, NHEAD, BB), 256, 0, stream>>>(
      qt, kt, vg, obf, lpart);
  combine_kernel<<<dim3(8, BB * NHEAD, 4), 256, 0, stream>>>(obf, lpart, attnT);
  out_mfma_kernel<<<dim3(NN / 64, BB, 4), 256, 0, stream>>>(attnT, wob, bo, x, out);
}

// Round 10
// 150.281 us; speedup vs baseline: 2.1430x; 2.1430x over previous
//
#include <hip/hip_runtime.h>
#include <hip/hip_bf16.h>

#define BB 4
#define CC 128
#define NN 4096
#define NHEAD 4
#define HDIM 32
#define KSPLIT 4   // attention m-dim split for occupancy

typedef short bf16x8_t __attribute__((ext_vector_type(8)));  // 8 bf16 (4 VGPRs)
typedef float f32x4_t __attribute__((ext_vector_type(4)));
typedef int i32x4_t __attribute__((ext_vector_type(4)));

#define MFMA16(a, b, c) __builtin_amdgcn_mfma_f32_16x16x32_bf16(a, b, c, 0, 0, 0)
#define EXP2(x) __builtin_amdgcn_exp2f(x)

// scores use exp2: fold log2(e) into q scale (softmax invariant)
#define QSCALE (0.17677669529663687f * 1.4426950408889634f)

// RNE float->bf16 (finite inputs only)
static __device__ inline unsigned short f2bf(float f) {
  unsigned u = __builtin_bit_cast(unsigned, f);
  u += 0x7fffu + ((u >> 16) & 1u);
  return (unsigned short)(u >> 16);
}
static __device__ inline unsigned pk2(float lo, float hi) {  // RNE pack pair
  return (unsigned)f2bf(lo) | ((unsigned)f2bf(hi) << 16);
}
// pack two f32 -> bf16 pair by TRUNCATION: single v_perm_b32
static __device__ inline unsigned pack_trunc(float lo, float hi) {
  return __builtin_amdgcn_perm(__builtin_bit_cast(unsigned, hi),
                               __builtin_bit_cast(unsigned, lo), 0x07060302u);
}
static __device__ inline float bfu_lo(unsigned v) {
  return __builtin_bit_cast(float, v << 16);
}
static __device__ inline float bfu_hi(unsigned v) {
  return __builtin_bit_cast(float, v & 0xFFFF0000u);
}

// async global->LDS, 16 B per lane. gsrc is PER-LANE (gather); LDS dest =
// uniform base + lane*16.
static __device__ inline void gload_lds16(const unsigned short* gsrc, void* ldst) {
  __builtin_amdgcn_global_load_lds(
      (const __attribute__((address_space(1))) unsigned int*)gsrc,
      (__attribute__((address_space(3))) unsigned int*)ldst, 16, 0, 0);
}

// RACE FIX (r10): global_load_lds raises vmcnt but its LDS write is not
// modeled as a dependency of later ds_reads; the barrier alone may not
// drain it. Force the drain explicitly before each __syncthreads.
static __device__ inline void waitcnt_vm0() {
  asm volatile("s_waitcnt vmcnt(0)" ::: "memory");
}

// ---------------------------------------------------------------------------
// W conversion: wq(*QSCALE), wk, wv, wo fp32 -> bf16, contiguous in wb.
// ---------------------------------------------------------------------------
__global__ __launch_bounds__(256) void wconv_kernel(
    const float* __restrict__ wq, const float* __restrict__ wk,
    const float* __restrict__ wv, const float* __restrict__ wo,
    unsigned short* __restrict__ wb) {
  int f = (blockIdx.x * 256 + threadIdx.x) * 8;  // 32 blocks -> 65536 elems
  int m = f >> 14, off = f & 16383;
  const float* src = (m == 0) ? wq : (m == 1) ? wk : (m == 2) ? wv : wo;
  float sc = (m == 0) ? QSCALE : 1.0f;
  float4 a = *(const float4*)(src + off);
  float4 b = *(const float4*)(src + off + 4);
  ushort4 u0, u1;
  u0.x = f2bf(a.x * sc); u0.y = f2bf(a.y * sc); u0.z = f2bf(a.z * sc); u0.w = f2bf(a.w * sc);
  u1.x = f2bf(b.x * sc); u1.y = f2bf(b.y * sc); u1.z = f2bf(b.z * sc); u1.w = f2bf(b.w * sc);
  *(ushort4*)(wb + f) = u0;
  *(ushort4*)(wb + f + 4) = u1;
}

// ---------------------------------------------------------------------------
// QKV projection via MFMA. Grid (64 ntiles, B, 3 proj x 2 ot-halves = 6).
//   Q/K: [b][h][dblk=d/8][n][8d] bf16 via shfl-paired uint4 stores.
//   V:   LDS transpose -> vg gathered tiles, sequential uint4.
// ---------------------------------------------------------------------------
__global__ __launch_bounds__(256) void qkv_mfma_kernel(
    const float* __restrict__ x,
    const unsigned short* __restrict__ wqb, const unsigned short* __restrict__ wkb,
    const unsigned short* __restrict__ wvb,
    const float* __restrict__ bq, const float* __restrict__ bk,
    const float* __restrict__ bv,
    unsigned short* __restrict__ qt, unsigned short* __restrict__ kt,
    unsigned short* __restrict__ vg) {
  __shared__ __attribute__((aligned(16))) unsigned short xsb[64][136];  // [n][c] bf16
  __shared__ unsigned short vt[64][66];                                 // [o_local][n] bf16
  const int b = blockIdx.y, nt = blockIdx.x;
  const int proj = blockIdx.z >> 1, half = blockIdx.z & 1;
  const int tid = threadIdx.x;

#pragma unroll
  for (int i = 0; i < 8; i++) {
    int f = tid + 256 * i;               // 0..2047 float4-slots
    int c = f >> 4, n4 = (f & 15) * 4;
    float4 v4 = *(const float4*)(x + ((size_t)b * CC + c) * NN + nt * 64 + n4);
    xsb[n4 + 0][c] = f2bf(v4.x);
    xsb[n4 + 1][c] = f2bf(v4.y);
    xsb[n4 + 2][c] = f2bf(v4.z);
    xsb[n4 + 3][c] = f2bf(v4.w);
  }
  __syncthreads();

  const int lane = tid & 63, w = tid >> 6;
  const int l16 = lane & 15, g = lane >> 4;
  const int nl = w * 16;
  const int ngl = nt * 64 + nl;

  bf16x8_t xf[4];
#pragma unroll
  for (int ks = 0; ks < 4; ks++)
    xf[ks] = *(const bf16x8_t*)&xsb[nl + l16][ks * 32 + g * 8];

  const unsigned short* wm = (proj == 0) ? wqb : (proj == 1) ? wkb : wvb;
  const float* bias = (proj == 0) ? bq : (proj == 1) ? bk : bv;
  const float bsc = (proj == 0) ? QSCALE : 1.0f;
  unsigned short* qkdst = proj ? kt : qt;

#pragma unroll
  for (int i = 0; i < 4; i++) {
    const int ot = half * 4 + i;
    f32x4_t acc;
#pragma unroll
    for (int r = 0; r < 4; r++) acc[r] = bias[ot * 16 + g * 4 + r] * bsc;
#pragma unroll
    for (int ks = 0; ks < 4; ks++) {
      bf16x8_t wf = *(const bf16x8_t*)(wm + (size_t)(ot * 16 + l16) * CC + ks * 32 + g * 8);
      acc = MFMA16(wf, xf[ks], acc);
    }
    if (proj < 2) {
      unsigned p0 = pk2(acc[0], acc[1]);
      unsigned p1 = pk2(acc[2], acc[3]);
      unsigned q0 = (unsigned)__shfl_xor((int)p0, 16);
      unsigned q1 = (unsigned)__shfl_xor((int)p1, 16);
      if ((g & 1) == 0) {
        int hh = ot >> 1, dblk = (ot & 1) * 2 + (g >> 1);
        unsigned short* dst =
            qkdst + (((size_t)(b * NHEAD + hh) * 4 + dblk) * NN + ngl + l16) * 8;
        uint4 val = make_uint4(p0, p1, q0, q1);
        *(uint4*)dst = val;
      }
    } else {
#pragma unroll
      for (int r = 0; r < 4; r++) vt[i * 16 + g * 4 + r][nl + l16] = f2bf(acc[r]);
    }
  }

  if (proj == 2) {
    __syncthreads();
    // emit this half's vg chunks: 512 16B chunks, sequential stores
#pragma unroll
    for (int c = 0; c < 2; c++) {
      int cid = c * 256 + tid;               // 0..511
      int hh_l = cid >> 8, inner = cid & 255;
      int hh = half * 2 + hh_l;
      int g2 = inner & 3, l16v = (inner >> 2) & 15, fh = inner >> 6;
      int fv = fh >> 1, halfv = fh & 1;
      int o_l = hh_l * 32 + halfv * 16 + l16v;   // local row in vt
      int n0 = fv * 32 + g2 * 4;
      unsigned d0 = *(const unsigned*)&vt[o_l][n0];
      unsigned d1 = *(const unsigned*)&vt[o_l][n0 + 2];
      unsigned d2 = *(const unsigned*)&vt[o_l][n0 + 16];
      unsigned d3 = *(const unsigned*)&vt[o_l][n0 + 18];
      uint4 val = make_uint4(d0, d1, d2, d3);
      *(uint4*)(vg + (((size_t)(b * NHEAD + hh) * 64 + nt) * 256 + inner) * 8) = val;
    }
  }
}

// ---------------------------------------------------------------------------
// Flash attention, bf16 MFMA, no online max (|scores| << 1, verified r2-7).
// KSPLIT=4 (2048 blocks -> 8 blocks/CU); launch_bounds(256,4) (r8's (256,8)
// spilled). Explicit s_waitcnt vmcnt(0) before each barrier fixes the
// global_load_lds -> ds_read race (r9 post-timing divergence).
// ---------------------------------------------------------------------------
__global__ __launch_bounds__(256, 4) void attn_mfma6_kernel(
    const unsigned short* __restrict__ qt, const unsigned short* __restrict__ kt,
    const unsigned short* __restrict__ vg,
    unsigned* __restrict__ obf, float* __restrict__ lpart) {
  __shared__ __attribute__((aligned(16))) unsigned short smem[2][4096];  // [buf]: K 2048, V 2048

  const int chunk = blockIdx.x & (KSPLIT - 1), nt = blockIdx.x / KSPLIT;  // nt 0..31
  const int h = blockIdx.y, b = blockIdx.z;
  const int bh = b * NHEAD + h;
  const int tid = threadIdx.x, lane = tid & 63, wid = tid >> 6;
  const int l16 = lane & 15, g = lane >> 4;
  const int nbase = nt * 128 + wid * 32;

  const unsigned short* qb = qt + (size_t)bh * NN * HDIM;  // [dblk][n][8]
  const unsigned short* kb = kt + (size_t)bh * NN * HDIM;
  const unsigned short* vgb = vg + (size_t)bh * 64 * 2048;

  const bf16x8_t qf0 = *(const bf16x8_t*)(qb + ((size_t)g * NN + nbase + l16) * 8);
  const bf16x8_t qf1 = *(const bf16x8_t*)(qb + ((size_t)g * NN + nbase + 16 + l16) * 8);

  f32x4_t o00 = {0, 0, 0, 0}, o01 = {0, 0, 0, 0};  // t0: d=g*4+r, d+16
  f32x4_t o10 = {0, 0, 0, 0}, o11 = {0, 0, 0, 0};  // t1
  float lA = 0.f, lB = 0.f;
  const f32x4_t zf = {0, 0, 0, 0};

  const int NITER = 64 / KSPLIT;        // 16
  const int mt0 = chunk * NITER;

  const unsigned short* ksrc = kb + ((size_t)g * NN + mt0 * 64 + wid * 16 + l16) * 8;
  const unsigned short* vsrc = vgb + (size_t)mt0 * 2048 + (size_t)((wid * 16 + l16) * 4 + g) * 8;

  auto stage = [&](int p, int i) {
    gload_lds16(ksrc + (size_t)i * 512, &smem[p][wid * 512]);
    gload_lds16(vsrc + (size_t)i * 2048, &smem[p][2048 + wid * 512]);
  };

  auto body = [&](int p) {
    const unsigned short* sk = &smem[p][0];
    bf16x8_t k0 = *(const bf16x8_t*)(sk + 0 * 512 + lane * 8);
    bf16x8_t k1 = *(const bf16x8_t*)(sk + 1 * 512 + lane * 8);
    bf16x8_t k2 = *(const bf16x8_t*)(sk + 2 * 512 + lane * 8);
    bf16x8_t k3 = *(const bf16x8_t*)(sk + 3 * 512 + lane * 8);
    bf16x8_t vf0 = *(const bf16x8_t*)(sk + 2048 + 0 * 512 + lane * 8);  // f0,h0
    bf16x8_t vf2 = *(const bf16x8_t*)(sk + 2048 + 1 * 512 + lane * 8);  // f0,h1
    bf16x8_t vf1 = *(const bf16x8_t*)(sk + 2048 + 2 * 512 + lane * 8);  // f1,h0
    bf16x8_t vf3 = *(const bf16x8_t*)(sk + 2048 + 3 * 512 + lane * 8);  // f1,h1

    f32x4_t sA0 = MFMA16(k0, qf0, zf), sA1 = MFMA16(k1, qf0, zf);
    f32x4_t sA2 = MFMA16(k2, qf0, zf), sA3 = MFMA16(k3, qf0, zf);
    f32x4_t sB0 = MFMA16(k0, qf1, zf), sB1 = MFMA16(k1, qf1, zf);
    f32x4_t sB2 = MFMA16(k2, qf1, zf), sB3 = MFMA16(k3, qf1, zf);

#pragma unroll
    for (int r = 0; r < 4; r++) {
      sA0[r] = EXP2(sA0[r]); sA1[r] = EXP2(sA1[r]);
      sA2[r] = EXP2(sA2[r]); sA3[r] = EXP2(sA3[r]);
      sB0[r] = EXP2(sB0[r]); sB1[r] = EXP2(sB1[r]);
      sB2[r] = EXP2(sB2[r]); sB3[r] = EXP2(sB3[r]);
      lA += (sA0[r] + sA1[r]) + (sA2[r] + sA3[r]);
      lB += (sB0[r] + sB1[r]) + (sB2[r] + sB3[r]);
    }

    i32x4_t pA0i = {(int)pack_trunc(sA0[0], sA0[1]), (int)pack_trunc(sA0[2], sA0[3]),
                    (int)pack_trunc(sA1[0], sA1[1]), (int)pack_trunc(sA1[2], sA1[3])};
    i32x4_t pA1i = {(int)pack_trunc(sA2[0], sA2[1]), (int)pack_trunc(sA2[2], sA2[3]),
                    (int)pack_trunc(sA3[0], sA3[1]), (int)pack_trunc(sA3[2], sA3[3])};
    i32x4_t pB0i = {(int)pack_trunc(sB0[0], sB0[1]), (int)pack_trunc(sB0[2], sB0[3]),
                    (int)pack_trunc(sB1[0], sB1[1]), (int)pack_trunc(sB1[2], sB1[3])};
    i32x4_t pB1i = {(int)pack_trunc(sB2[0], sB2[1]), (int)pack_trunc(sB2[2], sB2[3]),
                    (int)pack_trunc(sB3[0], sB3[1]), (int)pack_trunc(sB3[2], sB3[3])};
    bf16x8_t pA0 = __builtin_bit_cast(bf16x8_t, pA0i);
    bf16x8_t pA1 = __builtin_bit_cast(bf16x8_t, pA1i);
    bf16x8_t pB0 = __builtin_bit_cast(bf16x8_t, pB0i);
    bf16x8_t pB1 = __builtin_bit_cast(bf16x8_t, pB1i);

    o00 = MFMA16(vf0, pA0, o00); o00 = MFMA16(vf1, pA1, o00);
    o01 = MFMA16(vf2, pA0, o01); o01 = MFMA16(vf3, pA1, o01);
    o10 = MFMA16(vf0, pB0, o10); o10 = MFMA16(vf1, pB1, o10);
    o11 = MFMA16(vf2, pB0, o11); o11 = MFMA16(vf3, pB1, o11);
  };

  stage(0, 0);
  waitcnt_vm0();
  __syncthreads();
  for (int mi = 0; mi < NITER; mi += 2) {
    stage(1, mi + 1);
    body(0);
    waitcnt_vm0();   // drain buf1 staging before the barrier
    __syncthreads();
    if (mi + 2 < NITER) stage(0, mi + 2);
    body(1);
    waitcnt_vm0();   // drain buf0 staging before the barrier
    __syncthreads();
  }

  // l: lane-partial over its 16 m per col; reduce across the 4 g-quads
  lA += __shfl_xor(lA, 16); lA += __shfl_xor(lA, 32);
  lB += __shfl_xor(lB, 16); lB += __shfl_xor(lB, 32);

  // partial O as bf16 dword pairs: obf[(chunk*16+bh)*32d*2048 + d*2048 + dw]
  unsigned* ob = obf + (size_t)(chunk * BB * NHEAD + bh) * 32 * 2048;
  const int dw = (nbase >> 1) + l16;
#pragma unroll
  for (int r = 0; r < 4; r++) {
    ob[(size_t)(g * 4 + r) * 2048 + dw] = pk2(o00[r], o10[r]);
    ob[(size_t)(16 + g * 4 + r) * 2048 + dw] = pk2(o01[r], o11[r]);
  }
  if (g == 0) {
    float* lb_ = lpart + (size_t)(chunk * BB * NHEAD + bh) * NN;
    lb_[nbase + l16] = lA;
    lb_[nbase + 16 + l16] = lB;
  }
}

// ---------------------------------------------------------------------------
// Combine: sum KSPLIT bf16 partials, normalize, write attnT[b][n][c] bf16.
// Grid (8 dword-tiles, 16 bh, 4 dg). Thread handles one dword = 2 n.
// ---------------------------------------------------------------------------
__global__ __launch_bounds__(256) void combine_kernel(
    const unsigned* __restrict__ obf, const float* __restrict__ lpart,
    unsigned short* __restrict__ attnT) {
  const int dw = blockIdx.x * 256 + threadIdx.x;  // 0..2047
  const int bh = blockIdx.y, dg = blockIdx.z;
  const int b = bh >> 2, h = bh & 3;
  const int n0 = ((dw >> 4) << 5) + (dw & 15), n1 = n0 + 16;

  float l0 = 0.f, l1 = 0.f;
#pragma unroll
  for (int c = 0; c < KSPLIT; c++) {
    const float* lp = lpart + (size_t)(c * BB * NHEAD + bh) * NN;
    l0 += lp[n0];
    l1 += lp[n1];
  }
  float inv0 = 1.f / l0, inv1 = 1.f / l1;

  float s0[8], s1[8];
#pragma unroll
  for (int j = 0; j < 8; j++) { s0[j] = 0.f; s1[j] = 0.f; }
#pragma unroll
  for (int c = 0; c < KSPLIT; c++) {
    const unsigned* ob =
        obf + (size_t)(c * BB * NHEAD + bh) * 32 * 2048 + (size_t)dg * 8 * 2048 + dw;
#pragma unroll
    for (int j = 0; j < 8; j++) {
      unsigned v = ob[(size_t)j * 2048];
      s0[j] += bfu_lo(v);
      s1[j] += bfu_hi(v);
    }
  }
  unsigned w0[4], w1[4];
#pragma unroll
  for (int p = 0; p < 4; p++) {
    w0[p] = pk2(s0[2 * p] * inv0, s0[2 * p + 1] * inv0);
    w1[p] = pk2(s1[2 * p] * inv1, s1[2 * p + 1] * inv1);
  }
  unsigned short* d0 = attnT + ((size_t)b * NN + n0) * CC + h * HDIM + dg * 8;
  unsigned short* d1 = attnT + ((size_t)b * NN + n1) * CC + h * HDIM + dg * 8;
  *(uint4*)d0 = *(uint4*)&w0[0];
  *(uint4*)d1 = *(uint4*)&w1[0];
}

// ---------------------------------------------------------------------------
// Output projection via MFMA + bias + residual, fp32 out.
// Grid (64 ntiles, B, 4 channel-quarters).
// ---------------------------------------------------------------------------
__global__ __launch_bounds__(256) void out_mfma_kernel(
    const unsigned short* __restrict__ attnT, const unsigned short* __restrict__ wob,
    const float* __restrict__ bo, const float* __restrict__ x,
    float* __restrict__ out) {
  const int b = blockIdx.y, nt = blockIdx.x, quarter = blockIdx.z;
  const int tid = threadIdx.x, lane = tid & 63, w = tid >> 6;
  const int l16 = lane & 15, g = lane >> 4;
  const int n0 = nt * 64 + w * 16;

  bf16x8_t bf[4];
#pragma unroll
  for (int ks = 0; ks < 4; ks++)
    bf[ks] = *(const bf16x8_t*)(attnT + ((size_t)b * NN + n0 + l16) * CC + ks * 32 + g * 8);

#pragma unroll
  for (int mi = 0; mi < 2; mi++) {
    int mt = quarter * 2 + mi;
    f32x4_t acc;
#pragma unroll
    for (int r = 0; r < 4; r++) acc[r] = bo[mt * 16 + g * 4 + r];
#pragma unroll
    for (int ks = 0; ks < 4; ks++) {
      bf16x8_t af = *(const bf16x8_t*)(wob + (size_t)(mt * 16 + l16) * CC + ks * 32 + g * 8);
      acc = MFMA16(af, bf[ks], acc);
    }
#pragma unroll
    for (int r = 0; r < 4; r++) {
      int o = mt * 16 + g * 4 + r;
      size_t addr = ((size_t)b * CC + o) * NN + n0 + l16;
      out[addr] = acc[r] + x[addr];
    }
  }
}

extern "C" void kernel_launch(void* const* d_in, const int* in_sizes, int n_in,
                              void* d_out, int out_size, void* d_ws, size_t ws_size,
                              hipStream_t stream) {
  const float* x  = (const float*)d_in[0];
  const float* wq = (const float*)d_in[1];
  const float* bq = (const float*)d_in[2];
  const float* wk = (const float*)d_in[3];
  const float* bk = (const float*)d_in[4];
  const float* wv = (const float*)d_in[5];
  const float* bv = (const float*)d_in[6];
  const float* wo = (const float*)d_in[7];
  const float* bo = (const float*)d_in[8];
  float* out = (float*)d_out;

  char* w = (char*)d_ws;
  const size_t SZ = (size_t)BB * NHEAD * NN * HDIM * 2;  // 4 MB (bf16 buffer bytes)
  unsigned short* qt    = (unsigned short*)w;            // 4 MB (attnT aliases later)
  unsigned short* kt    = (unsigned short*)(w + SZ);     // 4 MB
  unsigned short* vg    = (unsigned short*)(w + 2 * SZ); // 4 MB (gathered V)
  unsigned short* wb    = (unsigned short*)(w + 3 * SZ); // 128 KB
  unsigned* obf = (unsigned*)(w + 3 * SZ + 131072);      // KSPLIT * 4 MB = 16 MB
  float* lpart = (float*)(w + 3 * SZ + 131072 +
                          (size_t)KSPLIT * BB * NHEAD * HDIM * NN * 2);  // KSPLIT * 256 KB
  unsigned short* attnT = qt;  // qt is dead once attention completes
  unsigned short* wqb = wb, *wkb = wb + 16384, *wvb = wb + 32768, *wob = wb + 49152;

  wconv_kernel<<<32, 256, 0, stream>>>(wq, wk, wv, wo, wb);
  qkv_mfma_kernel<<<dim3(NN / 64, BB, 6), 256, 0, stream>>>(
      x, wqb, wkb, wvb, bq, bk, bv, qt, kt, vg);
  attn_mfma6_kernel<<<dim3((NN / 128) * KSPLIT, NHEAD, BB), 256, 0, stream>>>(
      qt, kt, vg, obf, lpart);
  combine_kernel<<<dim3(8, BB * NHEAD, 4), 256, 0, stream>>>(obf, lpart, attnT);
  out_mfma_kernel<<<dim3(NN / 64, BB, 4), 256, 0, stream>>>(attnT, wob, bo, x, out);
}

// Round 11
// 149.375 us; speedup vs baseline: 2.1560x; 1.0061x over previous
//
#include <hip/hip_runtime.h>
#include <hip/hip_bf16.h>

#define BB 4
#define CC 128
#define NN 4096
#define NHEAD 4
#define HDIM 32
#define KSPLIT 4   // attention m-dim split for occupancy

typedef short bf16x8_t __attribute__((ext_vector_type(8)));  // 8 bf16 (4 VGPRs)
typedef float f32x4_t __attribute__((ext_vector_type(4)));
typedef int i32x4_t __attribute__((ext_vector_type(4)));

#define MFMA16(a, b, c) __builtin_amdgcn_mfma_f32_16x16x32_bf16(a, b, c, 0, 0, 0)
#define EXP2(x) __builtin_amdgcn_exp2f(x)

// scores use exp2: fold log2(e) into q scale (softmax invariant)
#define QSCALE (0.17677669529663687f * 1.4426950408889634f)

// RNE float->bf16 (finite inputs only)
static __device__ inline unsigned short f2bf(float f) {
  unsigned u = __builtin_bit_cast(unsigned, f);
  u += 0x7fffu + ((u >> 16) & 1u);
  return (unsigned short)(u >> 16);
}
static __device__ inline unsigned pk2(float lo, float hi) {  // RNE pack pair
  return (unsigned)f2bf(lo) | ((unsigned)f2bf(hi) << 16);
}
// pack two f32 -> bf16 pair by TRUNCATION: single v_perm_b32
static __device__ inline unsigned pack_trunc(float lo, float hi) {
  return __builtin_amdgcn_perm(__builtin_bit_cast(unsigned, hi),
                               __builtin_bit_cast(unsigned, lo), 0x07060302u);
}
static __device__ inline float bfu_lo(unsigned v) {
  return __builtin_bit_cast(float, v << 16);
}
static __device__ inline float bfu_hi(unsigned v) {
  return __builtin_bit_cast(float, v & 0xFFFF0000u);
}

// Build a bf16 MFMA fragment from 8 consecutive fp32 weights (in-register
// conversion; replaces the separate wconv kernel).
static __device__ inline bf16x8_t wfrag_f32(const float* __restrict__ Wp, float sc) {
  float4 a = *(const float4*)(Wp);
  float4 b = *(const float4*)(Wp + 4);
  i32x4_t pi = {(int)pk2(a.x * sc, a.y * sc), (int)pk2(a.z * sc, a.w * sc),
                (int)pk2(b.x * sc, b.y * sc), (int)pk2(b.z * sc, b.w * sc)};
  return __builtin_bit_cast(bf16x8_t, pi);
}

// async global->LDS, 16 B per lane. gsrc is PER-LANE (gather); LDS dest =
// uniform base + lane*16.
static __device__ inline void gload_lds16(const unsigned short* gsrc, void* ldst) {
  __builtin_amdgcn_global_load_lds(
      (const __attribute__((address_space(1))) unsigned int*)gsrc,
      (__attribute__((address_space(3))) unsigned int*)ldst, 16, 0, 0);
}

// RACE FIX (r10, keep): global_load_lds raises vmcnt but its LDS write is
// not modeled as a dependency of later ds_reads; drain before each barrier.
static __device__ inline void waitcnt_vm0() {
  asm volatile("s_waitcnt vmcnt(0)" ::: "memory");
}

// ---------------------------------------------------------------------------
// QKV projection via MFMA. Grid (64 ntiles, B, 3 proj x 2 ot-halves = 6).
// W converted fp32->bf16 in-register (wconv kernel eliminated).
//   Q/K: [b][h][dblk=d/8][n][8d] bf16 via shfl-paired uint4 stores.
//   V:   LDS transpose -> vg gathered tiles, sequential uint4.
// ---------------------------------------------------------------------------
__global__ __launch_bounds__(256) void qkv_mfma_kernel(
    const float* __restrict__ x,
    const float* __restrict__ wq, const float* __restrict__ wk,
    const float* __restrict__ wv,
    const float* __restrict__ bq, const float* __restrict__ bk,
    const float* __restrict__ bv,
    unsigned short* __restrict__ qt, unsigned short* __restrict__ kt,
    unsigned short* __restrict__ vg) {
  __shared__ __attribute__((aligned(16))) unsigned short xsb[64][136];  // [n][c] bf16
  __shared__ unsigned short vt[64][66];                                 // [o_local][n] bf16
  const int b = blockIdx.y, nt = blockIdx.x;
  const int proj = blockIdx.z >> 1, half = blockIdx.z & 1;
  const int tid = threadIdx.x;

#pragma unroll
  for (int i = 0; i < 8; i++) {
    int f = tid + 256 * i;               // 0..2047 float4-slots
    int c = f >> 4, n4 = (f & 15) * 4;
    float4 v4 = *(const float4*)(x + ((size_t)b * CC + c) * NN + nt * 64 + n4);
    xsb[n4 + 0][c] = f2bf(v4.x);
    xsb[n4 + 1][c] = f2bf(v4.y);
    xsb[n4 + 2][c] = f2bf(v4.z);
    xsb[n4 + 3][c] = f2bf(v4.w);
  }
  __syncthreads();

  const int lane = tid & 63, w = tid >> 6;
  const int l16 = lane & 15, g = lane >> 4;
  const int nl = w * 16;
  const int ngl = nt * 64 + nl;

  bf16x8_t xf[4];
#pragma unroll
  for (int ks = 0; ks < 4; ks++)
    xf[ks] = *(const bf16x8_t*)&xsb[nl + l16][ks * 32 + g * 8];

  const float* wm = (proj == 0) ? wq : (proj == 1) ? wk : wv;
  const float* bias = (proj == 0) ? bq : (proj == 1) ? bk : bv;
  const float bsc = (proj == 0) ? QSCALE : 1.0f;
  unsigned short* qkdst = proj ? kt : qt;

#pragma unroll
  for (int i = 0; i < 4; i++) {
    const int ot = half * 4 + i;
    f32x4_t acc;
#pragma unroll
    for (int r = 0; r < 4; r++) acc[r] = bias[ot * 16 + g * 4 + r] * bsc;
#pragma unroll
    for (int ks = 0; ks < 4; ks++) {
      bf16x8_t wf = wfrag_f32(wm + (size_t)(ot * 16 + l16) * CC + ks * 32 + g * 8, bsc);
      acc = MFMA16(wf, xf[ks], acc);
    }
    if (proj < 2) {
      unsigned p0 = pk2(acc[0], acc[1]);
      unsigned p1 = pk2(acc[2], acc[3]);
      unsigned q0 = (unsigned)__shfl_xor((int)p0, 16);
      unsigned q1 = (unsigned)__shfl_xor((int)p1, 16);
      if ((g & 1) == 0) {
        int hh = ot >> 1, dblk = (ot & 1) * 2 + (g >> 1);
        unsigned short* dst =
            qkdst + (((size_t)(b * NHEAD + hh) * 4 + dblk) * NN + ngl + l16) * 8;
        uint4 val = make_uint4(p0, p1, q0, q1);
        *(uint4*)dst = val;
      }
    } else {
#pragma unroll
      for (int r = 0; r < 4; r++) vt[i * 16 + g * 4 + r][nl + l16] = f2bf(acc[r]);
    }
  }

  if (proj == 2) {
    __syncthreads();
    // emit this half's vg chunks: 512 16B chunks, sequential stores
#pragma unroll
    for (int c = 0; c < 2; c++) {
      int cid = c * 256 + tid;               // 0..511
      int hh_l = cid >> 8, inner = cid & 255;
      int hh = half * 2 + hh_l;
      int g2 = inner & 3, l16v = (inner >> 2) & 15, fh = inner >> 6;
      int fv = fh >> 1, halfv = fh & 1;
      int o_l = hh_l * 32 + halfv * 16 + l16v;   // local row in vt
      int n0 = fv * 32 + g2 * 4;
      unsigned d0 = *(const unsigned*)&vt[o_l][n0];
      unsigned d1 = *(const unsigned*)&vt[o_l][n0 + 2];
      unsigned d2 = *(const unsigned*)&vt[o_l][n0 + 16];
      unsigned d3 = *(const unsigned*)&vt[o_l][n0 + 18];
      uint4 val = make_uint4(d0, d1, d2, d3);
      *(uint4*)(vg + (((size_t)(b * NHEAD + hh) * 64 + nt) * 256 + inner) * 8) = val;
    }
  }
}

// ---------------------------------------------------------------------------
// Flash attention, bf16 MFMA, no online max (|scores| << 1, verified r2-10).
// KSPLIT=4 (2048 blocks); launch_bounds(256,4); vmcnt(0) drain before each
// barrier (r10 race fix). ROUND 11: l restored to ones-MFMA (VALU was the
// hotter pipe at 54% vs MFMA 26%); removes 32 VALU adds + 2 shuffles/iter.
// ---------------------------------------------------------------------------
__global__ __launch_bounds__(256, 4) void attn_mfma7_kernel(
    const unsigned short* __restrict__ qt, const unsigned short* __restrict__ kt,
    const unsigned short* __restrict__ vg,
    unsigned* __restrict__ obf, float* __restrict__ lpart) {
  __shared__ __attribute__((aligned(16))) unsigned short smem[2][4096];  // [buf]: K 2048, V 2048

  const int chunk = blockIdx.x & (KSPLIT - 1), nt = blockIdx.x / KSPLIT;  // nt 0..31
  const int h = blockIdx.y, b = blockIdx.z;
  const int bh = b * NHEAD + h;
  const int tid = threadIdx.x, lane = tid & 63, wid = tid >> 6;
  const int l16 = lane & 15, g = lane >> 4;
  const int nbase = nt * 128 + wid * 32;

  const unsigned short* qb = qt + (size_t)bh * NN * HDIM;  // [dblk][n][8]
  const unsigned short* kb = kt + (size_t)bh * NN * HDIM;
  const unsigned short* vgb = vg + (size_t)bh * 64 * 2048;

  const bf16x8_t qf0 = *(const bf16x8_t*)(qb + ((size_t)g * NN + nbase + l16) * 8);
  const bf16x8_t qf1 = *(const bf16x8_t*)(qb + ((size_t)g * NN + nbase + 16 + l16) * 8);

  f32x4_t o00 = {0, 0, 0, 0}, o01 = {0, 0, 0, 0};  // t0: d=g*4+r, d+16
  f32x4_t o10 = {0, 0, 0, 0}, o11 = {0, 0, 0, 0};  // t1
  f32x4_t la = {0, 0, 0, 0}, lb = {0, 0, 0, 0};    // l via ones-MFMA
  const f32x4_t zf = {0, 0, 0, 0};
  const i32x4_t onesi = {0x3F803F80, 0x3F803F80, 0x3F803F80, 0x3F803F80};
  const bf16x8_t ones = __builtin_bit_cast(bf16x8_t, onesi);

  const int NITER = 64 / KSPLIT;        // 16
  const int mt0 = chunk * NITER;

  const unsigned short* ksrc = kb + ((size_t)g * NN + mt0 * 64 + wid * 16 + l16) * 8;
  const unsigned short* vsrc = vgb + (size_t)mt0 * 2048 + (size_t)((wid * 16 + l16) * 4 + g) * 8;

  auto stage = [&](int p, int i) {
    gload_lds16(ksrc + (size_t)i * 512, &smem[p][wid * 512]);
    gload_lds16(vsrc + (size_t)i * 2048, &smem[p][2048 + wid * 512]);
  };

  auto body = [&](int p) {
    const unsigned short* sk = &smem[p][0];
    bf16x8_t k0 = *(const bf16x8_t*)(sk + 0 * 512 + lane * 8);
    bf16x8_t k1 = *(const bf16x8_t*)(sk + 1 * 512 + lane * 8);
    bf16x8_t k2 = *(const bf16x8_t*)(sk + 2 * 512 + lane * 8);
    bf16x8_t k3 = *(const bf16x8_t*)(sk + 3 * 512 + lane * 8);
    bf16x8_t vf0 = *(const bf16x8_t*)(sk + 2048 + 0 * 512 + lane * 8);  // f0,h0
    bf16x8_t vf2 = *(const bf16x8_t*)(sk + 2048 + 1 * 512 + lane * 8);  // f0,h1
    bf16x8_t vf1 = *(const bf16x8_t*)(sk + 2048 + 2 * 512 + lane * 8);  // f1,h0
    bf16x8_t vf3 = *(const bf16x8_t*)(sk + 2048 + 3 * 512 + lane * 8);  // f1,h1

    f32x4_t sA0 = MFMA16(k0, qf0, zf), sA1 = MFMA16(k1, qf0, zf);
    f32x4_t sA2 = MFMA16(k2, qf0, zf), sA3 = MFMA16(k3, qf0, zf);
    f32x4_t sB0 = MFMA16(k0, qf1, zf), sB1 = MFMA16(k1, qf1, zf);
    f32x4_t sB2 = MFMA16(k2, qf1, zf), sB3 = MFMA16(k3, qf1, zf);

#pragma unroll
    for (int r = 0; r < 4; r++) {
      sA0[r] = EXP2(sA0[r]); sA1[r] = EXP2(sA1[r]);
      sA2[r] = EXP2(sA2[r]); sA3[r] = EXP2(sA3[r]);
      sB0[r] = EXP2(sB0[r]); sB1[r] = EXP2(sB1[r]);
      sB2[r] = EXP2(sB2[r]); sB3[r] = EXP2(sB3[r]);
    }

    i32x4_t pA0i = {(int)pack_trunc(sA0[0], sA0[1]), (int)pack_trunc(sA0[2], sA0[3]),
                    (int)pack_trunc(sA1[0], sA1[1]), (int)pack_trunc(sA1[2], sA1[3])};
    i32x4_t pA1i = {(int)pack_trunc(sA2[0], sA2[1]), (int)pack_trunc(sA2[2], sA2[3]),
                    (int)pack_trunc(sA3[0], sA3[1]), (int)pack_trunc(sA3[2], sA3[3])};
    i32x4_t pB0i = {(int)pack_trunc(sB0[0], sB0[1]), (int)pack_trunc(sB0[2], sB0[3]),
                    (int)pack_trunc(sB1[0], sB1[1]), (int)pack_trunc(sB1[2], sB1[3])};
    i32x4_t pB1i = {(int)pack_trunc(sB2[0], sB2[1]), (int)pack_trunc(sB2[2], sB2[3]),
                    (int)pack_trunc(sB3[0], sB3[1]), (int)pack_trunc(sB3[2], sB3[3])};
    bf16x8_t pA0 = __builtin_bit_cast(bf16x8_t, pA0i);
    bf16x8_t pA1 = __builtin_bit_cast(bf16x8_t, pA1i);
    bf16x8_t pB0 = __builtin_bit_cast(bf16x8_t, pB0i);
    bf16x8_t pB1 = __builtin_bit_cast(bf16x8_t, pB1i);

    o00 = MFMA16(vf0, pA0, o00); o00 = MFMA16(vf1, pA1, o00);
    o01 = MFMA16(vf2, pA0, o01); o01 = MFMA16(vf3, pA1, o01);
    o10 = MFMA16(vf0, pB0, o10); o10 = MFMA16(vf1, pB1, o10);
    o11 = MFMA16(vf2, pB0, o11); o11 = MFMA16(vf3, pB1, o11);

    la = MFMA16(ones, pA0, la); la = MFMA16(ones, pA1, la);
    lb = MFMA16(ones, pB0, lb); lb = MFMA16(ones, pB1, lb);
  };

  stage(0, 0);
  waitcnt_vm0();
  __syncthreads();
  for (int mi = 0; mi < NITER; mi += 2) {
    stage(1, mi + 1);
    body(0);
    waitcnt_vm0();   // drain buf1 staging before the barrier
    __syncthreads();
    if (mi + 2 < NITER) stage(0, mi + 2);
    body(1);
    waitcnt_vm0();   // drain buf0 staging before the barrier
    __syncthreads();
  }

  // partial O as bf16 dword pairs: obf[(chunk*16+bh)*32d*2048 + d*2048 + dw]
  unsigned* ob = obf + (size_t)(chunk * BB * NHEAD + bh) * 32 * 2048;
  const int dw = (nbase >> 1) + l16;
#pragma unroll
  for (int r = 0; r < 4; r++) {
    ob[(size_t)(g * 4 + r) * 2048 + dw] = pk2(o00[r], o10[r]);
    ob[(size_t)(16 + g * 4 + r) * 2048 + dw] = pk2(o01[r], o11[r]);
  }
  // la/lb rows all equal the column sum over this chunk's 64 m
  if (g == 0) {
    float* lb_ = lpart + (size_t)(chunk * BB * NHEAD + bh) * NN;
    lb_[nbase + l16] = la[0];
    lb_[nbase + 16 + l16] = lb[0];
  }
}

// ---------------------------------------------------------------------------
// Fused combine + output projection + bias + residual, fp32 out.
// Grid (128 32-n tiles, B). Block: combine KSPLIT obf partials -> normalized
// bf16 tile [32n][128c] in LDS, then wave w computes o-rows 32w..32w+31 via
// MFMA with in-register-converted Wo fragments. No attnT intermediate.
// ---------------------------------------------------------------------------
__global__ __launch_bounds__(256) void outc_kernel(
    const unsigned* __restrict__ obf, const float* __restrict__ lpart,
    const float* __restrict__ wo, const float* __restrict__ bo,
    const float* __restrict__ x, float* __restrict__ out) {
  __shared__ __attribute__((aligned(16))) unsigned short asb[32][136];  // [n_loc][c]
  const int b = blockIdx.y, nt2 = blockIdx.x;
  const int nb = nt2 * 32, dwb = nt2 * 16;
  const int tid = threadIdx.x, lane = tid & 63;
  const int wv = tid >> 6, l16 = lane & 15, g = lane >> 4;

  // --- combine: thread handles head h=wv, channels d = g*8..g*8+7, dword l16
  {
    float l0 = 0.f, l1 = 0.f;
#pragma unroll
    for (int c = 0; c < KSPLIT; c++) {
      const float* lp = lpart + (size_t)(c * BB * NHEAD + b * NHEAD + wv) * NN + nb;
      l0 += lp[l16];
      l1 += lp[16 + l16];
    }
    float inv0 = 1.f / l0, inv1 = 1.f / l1;
#pragma unroll
    for (int j = 0; j < 8; j++) {
      int d = g * 8 + j;
      float s0 = 0.f, s1 = 0.f;
#pragma unroll
      for (int c = 0; c < KSPLIT; c++) {
        unsigned v = obf[(size_t)(c * BB * NHEAD + b * NHEAD + wv) * 65536 +
                         (size_t)d * 2048 + dwb + l16];
        s0 += bfu_lo(v);
        s1 += bfu_hi(v);
      }
      int cfull = wv * 32 + d;
      asb[l16][cfull] = f2bf(s0 * inv0);
      asb[16 + l16][cfull] = f2bf(s1 * inv1);
    }
  }
  __syncthreads();

  // --- projection: wave wv owns o rows [wv*32, wv*32+32)
#pragma unroll
  for (int oi = 0; oi < 2; oi++) {
    const int ot = wv * 2 + oi;
    f32x4_t a0, a1;
#pragma unroll
    for (int r = 0; r < 4; r++) { a0[r] = bo[ot * 16 + g * 4 + r]; a1[r] = a0[r]; }
#pragma unroll
    for (int ks = 0; ks < 4; ks++) {
      bf16x8_t af = wfrag_f32(wo + (size_t)(ot * 16 + l16) * CC + ks * 32 + g * 8, 1.0f);
      bf16x8_t b0 = *(const bf16x8_t*)&asb[l16][ks * 32 + g * 8];
      bf16x8_t b1 = *(const bf16x8_t*)&asb[16 + l16][ks * 32 + g * 8];
      a0 = MFMA16(af, b0, a0);
      a1 = MFMA16(af, b1, a1);
    }
#pragma unroll
    for (int r = 0; r < 4; r++) {
      int o = ot * 16 + g * 4 + r;
      size_t ad = ((size_t)b * CC + o) * NN + nb + l16;
      out[ad] = a0[r] + x[ad];
      out[ad + 16] = a1[r] + x[ad + 16];
    }
  }
}

extern "C" void kernel_launch(void* const* d_in, const int* in_sizes, int n_in,
                              void* d_out, int out_size, void* d_ws, size_t ws_size,
                              hipStream_t stream) {
  const float* x  = (const float*)d_in[0];
  const float* wq = (const float*)d_in[1];
  const float* bq = (const float*)d_in[2];
  const float* wk = (const float*)d_in[3];
  const float* bk = (const float*)d_in[4];
  const float* wv = (const float*)d_in[5];
  const float* bv = (const float*)d_in[6];
  const float* wo = (const float*)d_in[7];
  const float* bo = (const float*)d_in[8];
  float* out = (float*)d_out;

  char* w = (char*)d_ws;
  const size_t SZ = (size_t)BB * NHEAD * NN * HDIM * 2;  // 4 MB (bf16 buffer bytes)
  unsigned short* qt = (unsigned short*)w;               // 4 MB
  unsigned short* kt = (unsigned short*)(w + SZ);        // 4 MB
  unsigned short* vg = (unsigned short*)(w + 2 * SZ);    // 4 MB (gathered V)
  unsigned* obf = (unsigned*)(w + 3 * SZ);               // KSPLIT * 4 MB = 16 MB
  float* lpart = (float*)(w + 3 * SZ +
                          (size_t)KSPLIT * BB * NHEAD * HDIM * NN * 2);  // 1 MB

  qkv_mfma_kernel<<<dim3(NN / 64, BB, 6), 256, 0, stream>>>(
      x, wq, wk, wv, bq, bk, bv, qt, kt, vg);
  attn_mfma7_kernel<<<dim3((NN / 128) * KSPLIT, NHEAD, BB), 256, 0, stream>>>(
      qt, kt, vg, obf, lpart);
  outc_kernel<<<dim3(NN / 32, BB), 256, 0, stream>>>(obf, lpart, wo, bo, x, out);
}